// Round 1
// baseline (5093.120 us; speedup 1.0000x reference)
//
#include <hip/hip_runtime.h>

#define NN 40000
#define DDEG 16
#define FF 128
#define OO 128
#define NG 512   // 4*F gates

typedef short  s16x8 __attribute__((ext_vector_type(8)));
typedef unsigned short u16x8 __attribute__((ext_vector_type(8)));
typedef float  f32x4 __attribute__((ext_vector_type(4)));

static_assert(sizeof(s16x8) == 16, "frag size");

__device__ __forceinline__ unsigned short f2bf(float f) {
    unsigned int u = __builtin_bit_cast(unsigned int, f);
    u += 0x7FFFu + ((u >> 16) & 1u);   // RNE
    return (unsigned short)(u >> 16);
}
__device__ __forceinline__ float bf2f(unsigned short s) {
    unsigned int u = ((unsigned int)s) << 16;
    return __builtin_bit_cast(float, u);
}
__device__ __forceinline__ float sigm(float x) {
    return __builtin_amdgcn_rcpf(1.0f + __expf(-x));
}
__device__ __forceinline__ float tanh_(float x) {
    float e = __expf(2.0f * x);
    return (e - 1.0f) * __builtin_amdgcn_rcpf(e + 1.0f);
}
__device__ __forceinline__ f32x4 splat4(float v) { f32x4 r = {v, v, v, v}; return r; }

// ---------------- prep: cast weights to bf16 (+ transpose Ws/Wn to [o][k]) ----
__global__ void k_prep(const float* __restrict__ Wih, const float* __restrict__ Whh,
                       const float* __restrict__ Ws,  const float* __restrict__ Wn,
                       unsigned short* __restrict__ wihb, unsigned short* __restrict__ whhb,
                       unsigned short* __restrict__ wstb, unsigned short* __restrict__ wntb) {
    int i = blockIdx.x * blockDim.x + threadIdx.x;
    int stride = gridDim.x * blockDim.x;
    for (int idx = i; idx < 4 * NG * FF; idx += stride) {
        wihb[idx] = f2bf(Wih[idx]);
        whhb[idx] = f2bf(Whh[idx]);
    }
    for (int idx = i; idx < 4 * FF * OO; idx += stride) {
        int r = idx >> 14;          // /(128*128)
        int rem = idx & 16383;
        int o = rem >> 7;
        int k = rem & 127;
        // dest [r][o][k] <- src [r][k][o]
        wstb[idx] = f2bf(Ws[(r << 14) + (k << 7) + o]);
        wntb[idx] = f2bf(Wn[(r << 14) + (k << 7) + o]);
    }
}

// ---------------- cast feat to bf16 ------------------------------------------
__global__ void k_castfeat(const float* __restrict__ feat, unsigned short* __restrict__ fbf) {
    int i = blockIdx.x * blockDim.x + threadIdx.x;
    int idx = i * 4;
    if (idx < NN * FF) {
        float4 v = *(const float4*)(feat + idx);
        ushort4 o;
        o.x = f2bf(v.x); o.y = f2bf(v.y); o.z = f2bf(v.z); o.w = f2bf(v.w);
        *(ushort4*)(fbf + idx) = o;
    }
}

// ---------------- segment mean (seg_ids sorted, G=64) ------------------------
__global__ void k_segmean(const float* __restrict__ feat, const int* __restrict__ seg,
                          float* __restrict__ mean) {
    int g = blockIdx.x;
    int lo, hi;
    { int a = 0, b = NN; while (a < b) { int m = (a + b) >> 1; if (seg[m] < g) a = m + 1; else b = m; } lo = a; }
    { int a = 0, b = NN; while (a < b) { int m = (a + b) >> 1; if (seg[m] < g + 1) a = m + 1; else b = m; } hi = a; }
    int dim  = threadIdx.x & 127;
    int half = threadIdx.x >> 7;
    float s = 0.f;
    for (int row = lo + half; row < hi; row += 2) s += feat[row * FF + dim];
    __shared__ float ps[256];
    ps[threadIdx.x] = s;
    __syncthreads();
    if (threadIdx.x < 128) {
        float tot = ps[threadIdx.x] + ps[threadIdx.x + 128];
        mean[g * FF + threadIdx.x] = tot / fmaxf((float)(hi - lo), 1.0f);
    }
}

// ---------------- deg bucketing ----------------------------------------------
// cnt[1..16]=counts, cnt[40+d]=cursor
__global__ void k_count(const int* __restrict__ deg, int* __restrict__ cnt) {
    int n = blockIdx.x * blockDim.x + threadIdx.x;
    if (n < NN) { int d = deg[n]; if (d > 0) atomicAdd(&cnt[d], 1); }
}
__global__ void k_offsets(int* __restrict__ cnt) {
    if (threadIdx.x == 0 && blockIdx.x == 0) {
        int running = 0;
        for (int d = 1; d <= 16; ++d) {
            cnt[40 + d] = running;
            running += (cnt[d] + 15) & ~15;   // pad each bucket to x16
        }
    }
}
__global__ void k_scatter(const int* __restrict__ deg, int* __restrict__ cnt, int* __restrict__ order) {
    int n = blockIdx.x * blockDim.x + threadIdx.x;
    if (n < NN) {
        int d = deg[n];
        if (d > 0) { int p = atomicAdd(&cnt[40 + d], 1); order[p] = n; }
    }
}

// ---------------- Xih = feat @ Wih[r].T + b, permuted storage ----------------
// perm: gate g=(tile*16+col) stored at [n][col*32 + tile]  (bf16, row=1024B)
__global__ __launch_bounds__(256) void k_xih(const unsigned short* __restrict__ fbf,
                                             const unsigned short* __restrict__ wihb,
                                             const float* __restrict__ lb,
                                             unsigned short* __restrict__ xih, int r) {
    int wv = threadIdx.x >> 6;
    int l  = threadIdx.x & 63;
    int n0 = blockIdx.x * 64 + wv * 16;
    int col = l & 15, grp = l >> 4;

    f32x4 acc[32];
#pragma unroll
    for (int t = 0; t < 32; ++t) acc[t] = splat4(lb[r * NG + t * 16 + col]);

    s16x8 a[4];
    const unsigned short* ap = fbf + (size_t)(n0 + col) * FF + grp * 8;
#pragma unroll
    for (int kt = 0; kt < 4; ++kt) a[kt] = *(const s16x8*)(ap + kt * 32);

    const unsigned short* wb = wihb + (size_t)r * NG * FF + col * FF + grp * 8;
#pragma unroll
    for (int t = 0; t < 32; ++t) {
#pragma unroll
        for (int kt = 0; kt < 4; ++kt) {
            s16x8 b = *(const s16x8*)(wb + t * 16 * FF + kt * 32);
            acc[t] = __builtin_amdgcn_mfma_f32_16x16x32_bf16(a[kt], b, acc[t], 0, 0, 0);
        }
    }
    __shared__ unsigned short lds[4][16][512];
#pragma unroll
    for (int t = 0; t < 32; ++t)
#pragma unroll
        for (int q = 0; q < 4; ++q)
            lds[wv][grp * 4 + q][col * 32 + t] = f2bf(acc[t][q]);
    __syncthreads();
    unsigned short* gout = xih + (size_t)n0 * NG;
    const unsigned short* lbase = &lds[wv][0][0];
#pragma unroll
    for (int i = 0; i < 16; ++i) {
        int byteoff = i * 1024 + l * 16;
        *(u16x8*)((char*)gout + byteoff) = *(const u16x8*)((const char*)lbase + byteoff);
    }
}

// ---------------- bucketed LSTM, 1 wave = 16 nodes of equal deg --------------
__global__ __launch_bounds__(64) void k_lstm(const unsigned short* __restrict__ xih,
                                             const unsigned short* __restrict__ whhb,
                                             const int* __restrict__ order,
                                             const int* __restrict__ nbr,
                                             const int* __restrict__ deg,
                                             unsigned short* __restrict__ hfin, int r) {
    __shared__ int nodes[16];
    __shared__ int nbrs[16][16];
    __shared__ unsigned short hl[2048];   // 16 rows x 128 dims bf16, XOR-swizzled
    int l = threadIdx.x;
    int g0 = blockIdx.x * 16;
    if (l < 16) nodes[l] = order[g0 + l];
    __syncthreads();
    if (nodes[0] < 0) return;
    int degv = deg[nodes[0]];

#pragma unroll
    for (int k = 0; k < 4; ++k) {
        int idx = l + k * 64;
        int row = idx >> 4, t = idx & 15;
        int nd = nodes[row]; if (nd < 0) nd = 0;
        nbrs[row][t] = nbr[nd * DDEG + t];
    }
    __syncthreads();

    int col = l & 15, grp = l >> 4;
    const unsigned short* wb = whhb + (size_t)r * NG * FF + col * FF + grp * 8;

    f32x4 c[8];
#pragma unroll
    for (int d = 0; d < 8; ++d) c[d] = splat4(0.f);

    for (int t = 0; t < degv; ++t) {
        f32x4 acc[32];
        // gather Xih rows (permuted layout) straight into D-frag positions
#pragma unroll
        for (int q = 0; q < 4; ++q) {
            int xn = nbrs[grp * 4 + q][t];
            const unsigned short* xp = xih + (size_t)xn * NG + col * 32;
#pragma unroll
            for (int ch = 0; ch < 4; ++ch) {
                u16x8 v = *(const u16x8*)(xp + ch * 8);
#pragma unroll
                for (int e = 0; e < 8; ++e) acc[ch * 8 + e][q] = bf2f(v[e]);
            }
        }
        if (t > 0) {
            s16x8 a[4];
#pragma unroll
            for (int kt = 0; kt < 4; ++kt) {
                int byte = (col * 256 + kt * 64 + grp * 16) ^ ((col & 7) << 4);
                a[kt] = *(const s16x8*)((const char*)hl + byte);
            }
#pragma unroll
            for (int nt = 0; nt < 32; ++nt) {
#pragma unroll
                for (int kt = 0; kt < 4; ++kt) {
                    s16x8 b = *(const s16x8*)(wb + nt * 16 * FF + kt * 32);
                    acc[nt] = __builtin_amdgcn_mfma_f32_16x16x32_bf16(a[kt], b, acc[nt], 0, 0, 0);
                }
            }
        }
        // activations + state update (i/f/g/o are lane-local across ntile strides of 8)
#pragma unroll
        for (int d = 0; d < 8; ++d) {
#pragma unroll
            for (int q = 0; q < 4; ++q) {
                float iv = sigm(acc[d][q]);
                float fv = sigm(acc[d + 8][q]);
                float gv = tanh_(acc[d + 16][q]);
                float ov = sigm(acc[d + 24][q]);
                float cv = fv * c[d][q] + iv * gv;
                c[d][q] = cv;
                float hv = ov * tanh_(cv);
                int row = grp * 4 + q;
                int byte = (row * 256 + (d * 16 + col) * 2) ^ ((row & 7) << 4);
                *(unsigned short*)((char*)hl + byte) = f2bf(hv);
            }
        }
        __syncthreads();
    }
    // write h_fin (bf16) for valid rows
#pragma unroll
    for (int i = 0; i < 4; ++i) {
        int byte = i * 1024 + l * 16;
        int row = byte >> 8;
        int within = byte & 255;
        int sb = (row * 256 + within) ^ ((row & 7) << 4);
        u16x8 v = *(const u16x8*)((const char*)hl + sb);
        int nd = nodes[row];
        if (nd >= 0) *(u16x8*)(hfin + (size_t)nd * FF + within / 2) = v;
    }
}

// ---------------- output projection + combine + residual ---------------------
__global__ __launch_bounds__(256) void k_proj(const unsigned short* __restrict__ fbf,
                                              const unsigned short* __restrict__ hfin,
                                              const unsigned short* __restrict__ wstb,
                                              const unsigned short* __restrict__ wntb,
                                              const float* __restrict__ bo,
                                              const float* __restrict__ mean,
                                              const int* __restrict__ seg,
                                              float* __restrict__ tmpA, float* __restrict__ tmpB,
                                              float* __restrict__ out, int r) {
    int wv = threadIdx.x >> 6, l = threadIdx.x & 63;
    int n0 = blockIdx.x * 64 + wv * 16;
    int col = l & 15, grp = l >> 4;

    f32x4 acc[8];
#pragma unroll
    for (int t = 0; t < 8; ++t) acc[t] = splat4(bo[r * OO + t * 16 + col]);

    const unsigned short* wsb = wstb + (size_t)r * OO * FF + col * FF + grp * 8;
    const unsigned short* wnb = wntb + (size_t)r * OO * FF + col * FF + grp * 8;
    const unsigned short* fp = fbf  + (size_t)(n0 + col) * FF + grp * 8;
    const unsigned short* hp = hfin + (size_t)(n0 + col) * FF + grp * 8;
#pragma unroll
    for (int kt = 0; kt < 4; ++kt) {
        s16x8 a = *(const s16x8*)(fp + kt * 32);
#pragma unroll
        for (int t = 0; t < 8; ++t) {
            s16x8 b = *(const s16x8*)(wsb + t * 16 * FF + kt * 32);
            acc[t] = __builtin_amdgcn_mfma_f32_16x16x32_bf16(a, b, acc[t], 0, 0, 0);
        }
    }
#pragma unroll
    for (int kt = 0; kt < 4; ++kt) {
        s16x8 a = *(const s16x8*)(hp + kt * 32);
#pragma unroll
        for (int t = 0; t < 8; ++t) {
            s16x8 b = *(const s16x8*)(wnb + t * 16 * FF + kt * 32);
            acc[t] = __builtin_amdgcn_mfma_f32_16x16x32_bf16(a, b, acc[t], 0, 0, 0);
        }
    }
#pragma unroll
    for (int q = 0; q < 4; ++q) {
        int node = n0 + grp * 4 + q;
        int sg = (r == 3) ? seg[node] : 0;
#pragma unroll
        for (int t = 0; t < 8; ++t) {
            int idx = node * OO + t * 16 + col;
            float p = acc[t][q];
            if (r == 0)      tmpA[idx] = p;
            else if (r == 1) tmpA[idx] = fmaxf(tmpA[idx], p);
            else if (r == 2) tmpB[idx] = p;
            else {
                float hb = fmaxf(tmpB[idx], p);
                out[idx] = mean[sg * FF + t * 16 + col] + tmpA[idx] + hb;
            }
        }
    }
}

extern "C" void kernel_launch(void* const* d_in, const int* in_sizes, int n_in,
                              void* d_out, int out_size, void* d_ws, size_t ws_size,
                              hipStream_t stream) {
    const float* feat = (const float*)d_in[0];
    const int* nbr[4] = {(const int*)d_in[1], (const int*)d_in[3], (const int*)d_in[5], (const int*)d_in[7]};
    const int* dgp[4] = {(const int*)d_in[2], (const int*)d_in[4], (const int*)d_in[6], (const int*)d_in[8]};
    const int* seg   = (const int*)d_in[9];
    const float* Wih = (const float*)d_in[10];
    const float* Whh = (const float*)d_in[11];
    const float* lb  = (const float*)d_in[12];
    const float* Ws  = (const float*)d_in[13];
    const float* Wn  = (const float*)d_in[14];
    const float* bo  = (const float*)d_in[15];

    char* ws = (char*)d_ws;
    float*          mean = (float*)(ws + 0);                      //  32768
    unsigned short* fbf  = (unsigned short*)(ws + 32768);         //  10,240,000
    unsigned short* wihb = (unsigned short*)(ws + 10272768);      //  524,288
    unsigned short* whhb = (unsigned short*)(ws + 10797056);      //  524,288
    unsigned short* wstb = (unsigned short*)(ws + 11321344);      //  131,072
    unsigned short* wntb = (unsigned short*)(ws + 11452416);      //  131,072
    unsigned short* xih  = (unsigned short*)(ws + 11583488);      //  40,960,000
    unsigned short* hfin = (unsigned short*)(ws + 52543488);      //  10,240,000
    float*          tmpA = (float*)(ws + 62783488);               //  20,480,000
    float*          tmpB = (float*)(ws + 83263488);               //  20,480,000
    int*            order= (int*)(ws + 103743488);                //  163,840
    int*            cnt  = (int*)(ws + 103907328);                //  256

    k_prep<<<256, 256, 0, stream>>>(Wih, Whh, Ws, Wn, wihb, whhb, wstb, wntb);
    k_castfeat<<<5000, 256, 0, stream>>>(feat, fbf);
    k_segmean<<<64, 256, 0, stream>>>(feat, seg, mean);

    for (int r = 0; r < 4; ++r) {
        hipMemsetAsync(order, 0xFF, 40960 * sizeof(int), stream);
        hipMemsetAsync(cnt, 0, 256, stream);
        hipMemsetAsync(hfin, 0, (size_t)NN * FF * 2, stream);
        k_count<<<157, 256, 0, stream>>>(dgp[r], cnt);
        k_offsets<<<1, 64, 0, stream>>>(cnt);
        k_scatter<<<157, 256, 0, stream>>>(dgp[r], cnt, order);
        k_xih<<<625, 256, 0, stream>>>(fbf, wihb, lb, xih, r);
        k_lstm<<<2560, 64, 0, stream>>>(xih, whhb, order, nbr[r], dgp[r], hfin, r);
        k_proj<<<625, 256, 0, stream>>>(fbf, hfin, wstb, wntb, bo, mean, seg,
                                        tmpA, tmpB, (float*)d_out, r);
    }
}

// Round 2
// 2311.800 us; speedup vs baseline: 2.2031x; 2.2031x over previous
//
#include <hip/hip_runtime.h>

#define NN 40000
#define DDEG 16
#define FF 128
#define OO 128
#define NG 512   // 4*F gates

typedef short  s16x8 __attribute__((ext_vector_type(8)));
typedef unsigned short u16x8 __attribute__((ext_vector_type(8)));
typedef float  f32x4 __attribute__((ext_vector_type(4)));

static_assert(sizeof(s16x8) == 16, "frag size");

__device__ __forceinline__ unsigned short f2bf(float f) {
    unsigned int u = __builtin_bit_cast(unsigned int, f);
    u += 0x7FFFu + ((u >> 16) & 1u);   // RNE
    return (unsigned short)(u >> 16);
}
__device__ __forceinline__ float bf2f(unsigned short s) {
    unsigned int u = ((unsigned int)s) << 16;
    return __builtin_bit_cast(float, u);
}
__device__ __forceinline__ float sigm(float x) {
    return __builtin_amdgcn_rcpf(1.0f + __expf(-x));
}
__device__ __forceinline__ float tanh_(float x) {
    float e = __expf(2.0f * x);
    return (e - 1.0f) * __builtin_amdgcn_rcpf(e + 1.0f);
}
__device__ __forceinline__ f32x4 splat4(float v) { f32x4 r = {v, v, v, v}; return r; }

// ---------------- prep: cast weights to bf16 (+ transpose Ws/Wn to [o][k]) ----
__global__ void k_prep(const float* __restrict__ Wih, const float* __restrict__ Whh,
                       const float* __restrict__ Ws,  const float* __restrict__ Wn,
                       unsigned short* __restrict__ wihb, unsigned short* __restrict__ whhb,
                       unsigned short* __restrict__ wstb, unsigned short* __restrict__ wntb) {
    int i = blockIdx.x * blockDim.x + threadIdx.x;
    int stride = gridDim.x * blockDim.x;
    for (int idx = i; idx < 4 * NG * FF; idx += stride) {
        wihb[idx] = f2bf(Wih[idx]);
        whhb[idx] = f2bf(Whh[idx]);
    }
    for (int idx = i; idx < 4 * FF * OO; idx += stride) {
        int r = idx >> 14;          // /(128*128)
        int rem = idx & 16383;
        int o = rem >> 7;
        int k = rem & 127;
        // dest [r][o][k] <- src [r][k][o]
        wstb[idx] = f2bf(Ws[(r << 14) + (k << 7) + o]);
        wntb[idx] = f2bf(Wn[(r << 14) + (k << 7) + o]);
    }
}

// ---------------- cast feat to bf16 ------------------------------------------
__global__ void k_castfeat(const float* __restrict__ feat, unsigned short* __restrict__ fbf) {
    int i = blockIdx.x * blockDim.x + threadIdx.x;
    int idx = i * 4;
    if (idx < NN * FF) {
        float4 v = *(const float4*)(feat + idx);
        ushort4 o;
        o.x = f2bf(v.x); o.y = f2bf(v.y); o.z = f2bf(v.z); o.w = f2bf(v.w);
        *(ushort4*)(fbf + idx) = o;
    }
}

// ---------------- segment mean (seg_ids sorted, G=64) ------------------------
__global__ void k_segmean(const float* __restrict__ feat, const int* __restrict__ seg,
                          float* __restrict__ mean) {
    int g = blockIdx.x;
    int lo, hi;
    { int a = 0, b = NN; while (a < b) { int m = (a + b) >> 1; if (seg[m] < g) a = m + 1; else b = m; } lo = a; }
    { int a = 0, b = NN; while (a < b) { int m = (a + b) >> 1; if (seg[m] < g + 1) a = m + 1; else b = m; } hi = a; }
    int dim  = threadIdx.x & 127;
    int half = threadIdx.x >> 7;
    float s = 0.f;
    for (int row = lo + half; row < hi; row += 2) s += feat[row * FF + dim];
    __shared__ float ps[256];
    ps[threadIdx.x] = s;
    __syncthreads();
    if (threadIdx.x < 128) {
        float tot = ps[threadIdx.x] + ps[threadIdx.x + 128];
        mean[g * FF + threadIdx.x] = tot / fmaxf((float)(hi - lo), 1.0f);
    }
}

// ---------------- deg bucketing ----------------------------------------------
// cnt[1..16]=counts, cnt[40+d]=cursor
__global__ void k_count(const int* __restrict__ deg, int* __restrict__ cnt) {
    int n = blockIdx.x * blockDim.x + threadIdx.x;
    if (n < NN) { int d = deg[n]; if (d > 0) atomicAdd(&cnt[d], 1); }
}
__global__ void k_offsets(int* __restrict__ cnt) {
    if (threadIdx.x == 0 && blockIdx.x == 0) {
        int running = 0;
        for (int d = 1; d <= 16; ++d) {
            cnt[40 + d] = running;
            running += (cnt[d] + 15) & ~15;   // pad each bucket to x16
        }
    }
}
__global__ void k_scatter(const int* __restrict__ deg, int* __restrict__ cnt, int* __restrict__ order) {
    int n = blockIdx.x * blockDim.x + threadIdx.x;
    if (n < NN) {
        int d = deg[n];
        if (d > 0) { int p = atomicAdd(&cnt[40 + d], 1); order[p] = n; }
    }
}

// ---------------- Xih = feat @ Wih[r].T + b, permuted storage ----------------
// perm: gate g=(tile*16+col) stored at [n][col*32 + tile]  (bf16, row=1024B)
// 4 waves per block, wave w computes tiles [8w, 8w+8) for the block's 16 nodes.
__global__ __launch_bounds__(256, 4) void k_xih(const unsigned short* __restrict__ fbf,
                                                const unsigned short* __restrict__ wihb,
                                                const float* __restrict__ lb,
                                                unsigned short* __restrict__ xih, int r) {
    int tid = threadIdx.x;
    int wv = tid >> 6;
    int l  = tid & 63;
    int n0 = blockIdx.x * 16;
    int col = l & 15, grp = l >> 4;

    f32x4 acc[8];
#pragma unroll
    for (int e = 0; e < 8; ++e) acc[e] = splat4(lb[r * NG + (wv * 8 + e) * 16 + col]);

    s16x8 a[4];
    const unsigned short* ap = fbf + (size_t)(n0 + col) * FF + grp * 8;
#pragma unroll
    for (int kt = 0; kt < 4; ++kt) a[kt] = *(const s16x8*)(ap + kt * 32);

    const unsigned short* wb = wihb + (size_t)r * NG * FF + (size_t)(wv * 8) * 16 * FF + col * FF + grp * 8;
#pragma unroll
    for (int e = 0; e < 8; ++e) {
#pragma unroll
        for (int kt = 0; kt < 4; ++kt) {
            s16x8 b = *(const s16x8*)(wb + e * 16 * FF + kt * 32);
            acc[e] = __builtin_amdgcn_mfma_f32_16x16x32_bf16(a[kt], b, acc[e], 0, 0, 0);
        }
    }
    __shared__ unsigned short lds[16][512];
#pragma unroll
    for (int e = 0; e < 8; ++e)
#pragma unroll
        for (int q = 0; q < 4; ++q)
            lds[grp * 4 + q][col * 32 + wv * 8 + e] = f2bf(acc[e][q]);
    __syncthreads();
    unsigned short* gout = xih + (size_t)n0 * NG;
    const unsigned short* lbase = &lds[0][0];
#pragma unroll
    for (int i = 0; i < 4; ++i) {
        int byteoff = (tid + i * 256) * 16;
        *(u16x8*)((char*)gout + byteoff) = *(const u16x8*)((const char*)lbase + byteoff);
    }
}

// ---------------- bucketed LSTM ----------------------------------------------
// 256 threads = 4 waves per block; block owns 16 nodes of equal deg.
// Wave w: gathers + MFMAs gate tiles [8w, 8w+8); gates exchanged via LDS (f32);
// activations owned per-thread as (node, 8 dims); h via XOR-swizzled LDS tile.
__global__ __launch_bounds__(256, 4) void k_lstm(const unsigned short* __restrict__ xih,
                                                 const unsigned short* __restrict__ whhb,
                                                 const int* __restrict__ order,
                                                 const int* __restrict__ nbr,
                                                 const int* __restrict__ deg,
                                                 unsigned short* __restrict__ hfin, int r) {
    __shared__ int nodes[16];
    __shared__ int nbrs[16][16];
    __shared__ unsigned short hl[2048];   // 16 rows x 128 dims bf16, XOR-swizzled
    __shared__ float gl[16][516];         // gates exchange, padded (+4) vs bank stride
    int tid = threadIdx.x;
    int wv = tid >> 6, l = tid & 63;
    int g0 = blockIdx.x * 16;
    if (tid < 16) nodes[tid] = order[g0 + tid];
    __syncthreads();
    if (nodes[0] < 0) return;
    int degv = deg[nodes[0]];

    {
        int row = tid >> 4, t = tid & 15;
        int nd = nodes[row]; if (nd < 0) nd = 0;
        nbrs[row][t] = nbr[nd * DDEG + t];
    }
    __syncthreads();

    int col = l & 15, grp = l >> 4;
    const unsigned short* wb = whhb + (size_t)r * NG * FF + (size_t)(wv * 8) * 16 * FF + col * FF + grp * 8;

    // activation ownership: thread -> (anode, dims [adim, adim+8))
    int anode = tid & 15;
    int adim  = (tid >> 4) * 8;
    float cst[8];
#pragma unroll
    for (int e = 0; e < 8; ++e) cst[e] = 0.f;

    for (int t = 0; t < degv; ++t) {
        f32x4 acc[8];
        // gather Xih chunk for this wave's 8 tiles, straight into D-frag positions
#pragma unroll
        for (int q = 0; q < 4; ++q) {
            int xn = nbrs[grp * 4 + q][t];
            u16x8 v = *(const u16x8*)(xih + (size_t)xn * NG + col * 32 + wv * 8);
#pragma unroll
            for (int e = 0; e < 8; ++e) acc[e][q] = bf2f(v[e]);
        }
        if (t > 0) {
            s16x8 a[4];
#pragma unroll
            for (int kt = 0; kt < 4; ++kt) {
                int byte = (col * 256 + kt * 64 + grp * 16) ^ ((col & 7) << 4);
                a[kt] = *(const s16x8*)((const char*)hl + byte);
            }
#pragma unroll
            for (int nt = 0; nt < 8; ++nt) {
#pragma unroll
                for (int kt = 0; kt < 4; ++kt) {
                    s16x8 b = *(const s16x8*)(wb + nt * 16 * FF + kt * 32);
                    acc[nt] = __builtin_amdgcn_mfma_f32_16x16x32_bf16(a[kt], b, acc[nt], 0, 0, 0);
                }
            }
        }
        // publish gates to LDS: gate index = (wv*8+nt)*16 + col, node = grp*4+q
#pragma unroll
        for (int nt = 0; nt < 8; ++nt)
#pragma unroll
            for (int q = 0; q < 4; ++q)
                gl[grp * 4 + q][(wv * 8 + nt) * 16 + col] = acc[nt][q];
        __syncthreads();
        // activations + state update
        unsigned short hb[8];
#pragma unroll
        for (int e = 0; e < 8; ++e) {
            int d = adim + e;
            float iv = sigm(gl[anode][d]);
            float fv = sigm(gl[anode][d + 128]);
            float gv = tanh_(gl[anode][d + 256]);
            float ov = sigm(gl[anode][d + 384]);
            float cv = fv * cst[e] + iv * gv;
            cst[e] = cv;
            hb[e] = f2bf(ov * tanh_(cv));
        }
        int hbyte = (anode * 256 + adim * 2) ^ ((anode & 7) << 4);
        *(u16x8*)((char*)hl + hbyte) = *(const u16x8*)hb;
        __syncthreads();
    }
    // write h_fin (bf16) for valid rows; loop ended on a barrier so hl is coherent
    int nd = nodes[anode];
    if (nd >= 0) {
        int hbyte = (anode * 256 + adim * 2) ^ ((anode & 7) << 4);
        u16x8 v = *(const u16x8*)((const char*)hl + hbyte);
        *(u16x8*)(hfin + (size_t)nd * FF + adim) = v;
    }
}

// ---------------- output projection + combine + residual ---------------------
__global__ __launch_bounds__(256) void k_proj(const unsigned short* __restrict__ fbf,
                                              const unsigned short* __restrict__ hfin,
                                              const unsigned short* __restrict__ wstb,
                                              const unsigned short* __restrict__ wntb,
                                              const float* __restrict__ bo,
                                              const float* __restrict__ mean,
                                              const int* __restrict__ seg,
                                              float* __restrict__ tmpA, float* __restrict__ tmpB,
                                              float* __restrict__ out, int r) {
    int wv = threadIdx.x >> 6, l = threadIdx.x & 63;
    int n0 = blockIdx.x * 64 + wv * 16;
    int col = l & 15, grp = l >> 4;

    f32x4 acc[8];
#pragma unroll
    for (int t = 0; t < 8; ++t) acc[t] = splat4(bo[r * OO + t * 16 + col]);

    const unsigned short* wsb = wstb + (size_t)r * OO * FF + col * FF + grp * 8;
    const unsigned short* wnb = wntb + (size_t)r * OO * FF + col * FF + grp * 8;
    const unsigned short* fp = fbf  + (size_t)(n0 + col) * FF + grp * 8;
    const unsigned short* hp = hfin + (size_t)(n0 + col) * FF + grp * 8;
#pragma unroll
    for (int kt = 0; kt < 4; ++kt) {
        s16x8 a = *(const s16x8*)(fp + kt * 32);
#pragma unroll
        for (int t = 0; t < 8; ++t) {
            s16x8 b = *(const s16x8*)(wsb + t * 16 * FF + kt * 32);
            acc[t] = __builtin_amdgcn_mfma_f32_16x16x32_bf16(a, b, acc[t], 0, 0, 0);
        }
    }
#pragma unroll
    for (int kt = 0; kt < 4; ++kt) {
        s16x8 a = *(const s16x8*)(hp + kt * 32);
#pragma unroll
        for (int t = 0; t < 8; ++t) {
            s16x8 b = *(const s16x8*)(wnb + t * 16 * FF + kt * 32);
            acc[t] = __builtin_amdgcn_mfma_f32_16x16x32_bf16(a, b, acc[t], 0, 0, 0);
        }
    }
#pragma unroll
    for (int q = 0; q < 4; ++q) {
        int node = n0 + grp * 4 + q;
        int sg = (r == 3) ? seg[node] : 0;
#pragma unroll
        for (int t = 0; t < 8; ++t) {
            int idx = node * OO + t * 16 + col;
            float p = acc[t][q];
            if (r == 0)      tmpA[idx] = p;
            else if (r == 1) tmpA[idx] = fmaxf(tmpA[idx], p);
            else if (r == 2) tmpB[idx] = p;
            else {
                float hb = fmaxf(tmpB[idx], p);
                out[idx] = mean[sg * FF + t * 16 + col] + tmpA[idx] + hb;
            }
        }
    }
}

extern "C" void kernel_launch(void* const* d_in, const int* in_sizes, int n_in,
                              void* d_out, int out_size, void* d_ws, size_t ws_size,
                              hipStream_t stream) {
    const float* feat = (const float*)d_in[0];
    const int* nbr[4] = {(const int*)d_in[1], (const int*)d_in[3], (const int*)d_in[5], (const int*)d_in[7]};
    const int* dgp[4] = {(const int*)d_in[2], (const int*)d_in[4], (const int*)d_in[6], (const int*)d_in[8]};
    const int* seg   = (const int*)d_in[9];
    const float* Wih = (const float*)d_in[10];
    const float* Whh = (const float*)d_in[11];
    const float* lb  = (const float*)d_in[12];
    const float* Ws  = (const float*)d_in[13];
    const float* Wn  = (const float*)d_in[14];
    const float* bo  = (const float*)d_in[15];

    char* ws = (char*)d_ws;
    float*          mean = (float*)(ws + 0);                      //  32768
    unsigned short* fbf  = (unsigned short*)(ws + 32768);         //  10,240,000
    unsigned short* wihb = (unsigned short*)(ws + 10272768);      //  524,288
    unsigned short* whhb = (unsigned short*)(ws + 10797056);      //  524,288
    unsigned short* wstb = (unsigned short*)(ws + 11321344);      //  131,072
    unsigned short* wntb = (unsigned short*)(ws + 11452416);      //  131,072
    unsigned short* xih  = (unsigned short*)(ws + 11583488);      //  40,960,000
    unsigned short* hfin = (unsigned short*)(ws + 52543488);      //  10,240,000
    float*          tmpA = (float*)(ws + 62783488);               //  20,480,000
    float*          tmpB = (float*)(ws + 83263488);               //  20,480,000
    int*            order= (int*)(ws + 103743488);                //  163,840
    int*            cnt  = (int*)(ws + 103907328);                //  256

    k_prep<<<256, 256, 0, stream>>>(Wih, Whh, Ws, Wn, wihb, whhb, wstb, wntb);
    k_castfeat<<<5000, 256, 0, stream>>>(feat, fbf);
    k_segmean<<<64, 256, 0, stream>>>(feat, seg, mean);

    for (int r = 0; r < 4; ++r) {
        hipMemsetAsync(order, 0xFF, 40960 * sizeof(int), stream);
        hipMemsetAsync(cnt, 0, 256, stream);
        hipMemsetAsync(hfin, 0, (size_t)NN * FF * 2, stream);
        k_count<<<157, 256, 0, stream>>>(dgp[r], cnt);
        k_offsets<<<1, 64, 0, stream>>>(cnt);
        k_scatter<<<157, 256, 0, stream>>>(dgp[r], cnt, order);
        k_xih<<<2500, 256, 0, stream>>>(fbf, wihb, lb, xih, r);
        k_lstm<<<2560, 256, 0, stream>>>(xih, whhb, order, nbr[r], dgp[r], hfin, r);
        k_proj<<<625, 256, 0, stream>>>(fbf, hfin, wstb, wntb, bo, mean, seg,
                                        tmpA, tmpB, (float*)d_out, r);
    }
}

// Round 3
// 1679.147 us; speedup vs baseline: 3.0332x; 1.3768x over previous
//
#include <hip/hip_runtime.h>

#define NN 40000
#define DDEG 16
#define FF 128
#define OO 128
#define NG 512   // 4*F gates

typedef short  s16x8 __attribute__((ext_vector_type(8)));
typedef unsigned short u16x8 __attribute__((ext_vector_type(8)));
typedef float  f32x4 __attribute__((ext_vector_type(4)));

static_assert(sizeof(s16x8) == 16, "frag size");

__device__ __forceinline__ unsigned short f2bf(float f) {
    unsigned int u = __builtin_bit_cast(unsigned int, f);
    u += 0x7FFFu + ((u >> 16) & 1u);   // RNE
    return (unsigned short)(u >> 16);
}
__device__ __forceinline__ float bf2f(unsigned short s) {
    unsigned int u = ((unsigned int)s) << 16;
    return __builtin_bit_cast(float, u);
}
__device__ __forceinline__ float sigm(float x) {
    return __builtin_amdgcn_rcpf(1.0f + __expf(-x));
}
__device__ __forceinline__ float tanh_(float x) {
    float e = __expf(2.0f * x);
    return (e - 1.0f) * __builtin_amdgcn_rcpf(e + 1.0f);
}
__device__ __forceinline__ f32x4 splat4(float v) { f32x4 r = {v, v, v, v}; return r; }

// ---------------- prep: cast weights to bf16 (+ transpose Ws/Wn to [o][k]) ----
__global__ void k_prep(const float* __restrict__ Wih, const float* __restrict__ Whh,
                       const float* __restrict__ Ws,  const float* __restrict__ Wn,
                       unsigned short* __restrict__ wihb, unsigned short* __restrict__ whhb,
                       unsigned short* __restrict__ wstb, unsigned short* __restrict__ wntb) {
    int i = blockIdx.x * blockDim.x + threadIdx.x;
    int stride = gridDim.x * blockDim.x;
    for (int idx = i; idx < 4 * NG * FF; idx += stride) {
        wihb[idx] = f2bf(Wih[idx]);
        whhb[idx] = f2bf(Whh[idx]);
    }
    for (int idx = i; idx < 4 * FF * OO; idx += stride) {
        int r = idx >> 14;          // /(128*128)
        int rem = idx & 16383;
        int o = rem >> 7;
        int k = rem & 127;
        // dest [r][o][k] <- src [r][k][o]
        wstb[idx] = f2bf(Ws[(r << 14) + (k << 7) + o]);
        wntb[idx] = f2bf(Wn[(r << 14) + (k << 7) + o]);
    }
}

// ---------------- cast feat to bf16 ------------------------------------------
__global__ void k_castfeat(const float* __restrict__ feat, unsigned short* __restrict__ fbf) {
    int i = blockIdx.x * blockDim.x + threadIdx.x;
    int idx = i * 4;
    if (idx < NN * FF) {
        float4 v = *(const float4*)(feat + idx);
        ushort4 o;
        o.x = f2bf(v.x); o.y = f2bf(v.y); o.z = f2bf(v.z); o.w = f2bf(v.w);
        *(ushort4*)(fbf + idx) = o;
    }
}

// ---------------- segment mean (seg_ids sorted, G=64), float4 vectorized -----
__global__ void k_segmean(const float* __restrict__ feat, const int* __restrict__ seg,
                          float* __restrict__ mean) {
    int g = blockIdx.x;
    int lo, hi;
    { int a = 0, b = NN; while (a < b) { int m = (a + b) >> 1; if (seg[m] < g) a = m + 1; else b = m; } lo = a; }
    { int a = 0, b = NN; while (a < b) { int m = (a + b) >> 1; if (seg[m] < g + 1) a = m + 1; else b = m; } hi = a; }
    int tid = threadIdx.x;
    int d4 = tid & 31;          // float4 slot: dims [d4*4, d4*4+4)
    int part = tid >> 5;        // 8 row-partitions
    float4 s = {0.f, 0.f, 0.f, 0.f};
    for (int row = lo + part; row < hi; row += 8) {
        float4 v = *(const float4*)(feat + (size_t)row * FF + d4 * 4);
        s.x += v.x; s.y += v.y; s.z += v.z; s.w += v.w;
    }
    __shared__ float ps[8][128];
    ps[part][d4 * 4 + 0] = s.x; ps[part][d4 * 4 + 1] = s.y;
    ps[part][d4 * 4 + 2] = s.z; ps[part][d4 * 4 + 3] = s.w;
    __syncthreads();
    if (tid < 128) {
        float tot = 0.f;
#pragma unroll
        for (int p = 0; p < 8; ++p) tot += ps[p][tid];
        mean[g * FF + tid] = tot / fmaxf((float)(hi - lo), 1.0f);
    }
}

// ---------------- deg bucketing, all 4 relations -----------------------------
// cnt4[r*64 + d] = counts (d=1..16), cnt4[r*64 + 40 + d] = cursor
__global__ void k_count(const int* __restrict__ D0, const int* __restrict__ D1,
                        const int* __restrict__ D2, const int* __restrict__ D3,
                        int* __restrict__ cnt4) {
    int r = blockIdx.y;
    const int* dg = (r == 0) ? D0 : (r == 1) ? D1 : (r == 2) ? D2 : D3;
    int n = blockIdx.x * blockDim.x + threadIdx.x;
    if (n < NN) { int d = dg[n]; if (d > 0) atomicAdd(&cnt4[r * 64 + d], 1); }
}
__global__ void k_offsets(int* __restrict__ cnt4) {
    int r = threadIdx.x;
    if (r < 4 && blockIdx.x == 0) {
        int running = 0;
        for (int d = 1; d <= 16; ++d) {
            cnt4[r * 64 + 40 + d] = running;
            running += (cnt4[r * 64 + d] + 15) & ~15;   // pad each bucket to x16
        }
    }
}
__global__ void k_scatter(const int* __restrict__ D0, const int* __restrict__ D1,
                          const int* __restrict__ D2, const int* __restrict__ D3,
                          int* __restrict__ cnt4, int* __restrict__ order4) {
    int r = blockIdx.y;
    const int* dg = (r == 0) ? D0 : (r == 1) ? D1 : (r == 2) ? D2 : D3;
    int n = blockIdx.x * blockDim.x + threadIdx.x;
    if (n < NN) {
        int d = dg[n];
        if (d > 0) { int p = atomicAdd(&cnt4[r * 64 + 40 + d], 1); order4[r * 40960 + p] = n; }
    }
}

// ---------------- Xih = feat @ Wih[r].T + b, wave-permuted storage ----------
// Wave w owns gate-tiles {w+4j : j=0..7}. Row layout (512 u16 = 1KB):
// u16 index w*128 + col*8 + j  holds gate (w+4j)*16+col.
// No LDS: pack acc per q into u16x8, store directly.
__global__ __launch_bounds__(256, 4) void k_xih(const unsigned short* __restrict__ fbf,
                                                const unsigned short* __restrict__ wihb,
                                                const float* __restrict__ lb,
                                                unsigned short* __restrict__ xih, int r) {
    int tid = threadIdx.x;
    int w = tid >> 6;
    int l = tid & 63;
    int n0 = blockIdx.x * 16;
    int col = l & 15, grp = l >> 4;

    f32x4 acc[8];
#pragma unroll
    for (int j = 0; j < 8; ++j) acc[j] = splat4(lb[r * NG + (w + 4 * j) * 16 + col]);

    s16x8 a[4];
    const unsigned short* ap = fbf + (size_t)(n0 + col) * FF + grp * 8;
#pragma unroll
    for (int kt = 0; kt < 4; ++kt) a[kt] = *(const s16x8*)(ap + kt * 32);

    const unsigned short* wb = wihb + (size_t)r * NG * FF + col * FF + grp * 8;
#pragma unroll
    for (int j = 0; j < 8; ++j) {
#pragma unroll
        for (int kt = 0; kt < 4; ++kt) {
            s16x8 b = *(const s16x8*)(wb + (size_t)(w + 4 * j) * 16 * FF + kt * 32);
            acc[j] = __builtin_amdgcn_mfma_f32_16x16x32_bf16(a[kt], b, acc[j], 0, 0, 0);
        }
    }
#pragma unroll
    for (int q = 0; q < 4; ++q) {
        u16x8 hv;
#pragma unroll
        for (int j = 0; j < 8; ++j) hv[j] = f2bf(acc[j][q]);
        *(u16x8*)(xih + (size_t)(n0 + grp * 4 + q) * NG + w * 128 + col * 8) = hv;
    }
}

// ---------------- bucketed LSTM ----------------------------------------------
// 256 thr = 4 waves; block owns 16 nodes of equal deg. Wave w owns tiles
// {w+4j}; i/f/g/o quadruples are thread-local (acc[ji],acc[ji+2],acc[ji+4],
// acc[ji+6]); activations fully in-register; h via double-buffered swizzled
// LDS; ONE barrier per step.
__global__ __launch_bounds__(256, 4) void k_lstm(const unsigned short* __restrict__ xih,
                                                 const unsigned short* __restrict__ whhb,
                                                 const int* __restrict__ order,
                                                 const int* __restrict__ nbr,
                                                 const int* __restrict__ deg,
                                                 unsigned short* __restrict__ hfin, int r) {
    __shared__ int nodes[16];
    __shared__ int nbrs[16][16];
    __shared__ unsigned short hbuf[2][2048];   // 2 x (16 rows x 128 dims bf16), XOR-swizzled
    int tid = threadIdx.x;
    int w = tid >> 6, l = tid & 63;
    int g0 = blockIdx.x * 16;
    if (tid < 16) nodes[tid] = order[g0 + tid];
    __syncthreads();
    if (nodes[0] < 0) return;
    int degv = deg[nodes[0]];

    {
        int row = tid >> 4, t = tid & 15;
        int nd = nodes[row]; if (nd < 0) nd = 0;
        nbrs[row][t] = nbr[nd * DDEG + t];
    }
    __syncthreads();

    int col = l & 15, grp = l >> 4;
    const unsigned short* wb = whhb + (size_t)r * NG * FF + col * FF + grp * 8;
    const unsigned short* xb = xih + w * 128 + col * 8;

    float cst[8];
#pragma unroll
    for (int e = 0; e < 8; ++e) cst[e] = 0.f;

    for (int t = 0; t < degv; ++t) {
        f32x4 acc[8];
        // gather Xih (wave-permuted layout): one u16x8 per node, lands in D-frag
#pragma unroll
        for (int q = 0; q < 4; ++q) {
            int xn = nbrs[grp * 4 + q][t];
            u16x8 v = *(const u16x8*)(xb + (size_t)xn * NG);
#pragma unroll
            for (int j = 0; j < 8; ++j) acc[j][q] = bf2f(v[j]);
        }
        if (t > 0) {
            const char* hrd = (const char*)hbuf[t & 1];
            s16x8 a[4];
#pragma unroll
            for (int kt = 0; kt < 4; ++kt) {
                int byte = (col * 256 + kt * 64 + grp * 16) ^ ((col & 7) << 4);
                a[kt] = *(const s16x8*)(hrd + byte);
            }
#pragma unroll
            for (int j = 0; j < 8; ++j) {
#pragma unroll
                for (int kt = 0; kt < 4; ++kt) {
                    s16x8 b = *(const s16x8*)(wb + (size_t)(w + 4 * j) * 16 * FF + kt * 32);
                    acc[j] = __builtin_amdgcn_mfma_f32_16x16x32_bf16(a[kt], b, acc[j], 0, 0, 0);
                }
            }
        }
        // in-register activations; write h to the other buffer
        char* hwr = (char*)hbuf[(t + 1) & 1];
#pragma unroll
        for (int ji = 0; ji < 2; ++ji) {
#pragma unroll
            for (int q = 0; q < 4; ++q) {
                float iv = sigm(acc[ji][q]);
                float fv = sigm(acc[ji + 2][q]);
                float gv = tanh_(acc[ji + 4][q]);
                float ov = sigm(acc[ji + 6][q]);
                float cv = fv * cst[ji * 4 + q] + iv * gv;
                cst[ji * 4 + q] = cv;
                float hv = ov * tanh_(cv);
                int node = grp * 4 + q;
                int dim = (w + 4 * ji) * 16 + col;
                int byte = (node * 256 + dim * 2) ^ ((node & 7) << 4);
                *(unsigned short*)(hwr + byte) = f2bf(hv);
            }
        }
        __syncthreads();
    }
    // write h_fin from hbuf[degv & 1]
    const char* hf = (const char*)hbuf[degv & 1];
    int row = tid >> 4;
    int nd = nodes[row];
    if (nd >= 0) {
        int off = (tid & 15) * 16;                    // byte within row
        int byte = (row * 256 + off) ^ ((row & 7) << 4);
        u16x8 v = *(const u16x8*)(hf + byte);
        *(u16x8*)(hfin + (size_t)nd * FF + off / 2) = v;
    }
}

// ---------------- fused projection: all 4 r + max/add + residual -------------
__global__ __launch_bounds__(256, 2) void k_proj(const unsigned short* __restrict__ fbf,
                                                 const unsigned short* __restrict__ hfin4,
                                                 const unsigned short* __restrict__ wstb,
                                                 const unsigned short* __restrict__ wntb,
                                                 const float* __restrict__ bo,
                                                 const float* __restrict__ mean,
                                                 const int* __restrict__ seg,
                                                 float* __restrict__ out) {
    int wv = threadIdx.x >> 6, l = threadIdx.x & 63;
    int n0 = blockIdx.x * 64 + wv * 16;
    int col = l & 15, grp = l >> 4;

    s16x8 af[4];
    const unsigned short* fp = fbf + (size_t)(n0 + col) * FF + grp * 8;
#pragma unroll
    for (int kt = 0; kt < 4; ++kt) af[kt] = *(const s16x8*)(fp + kt * 32);

    f32x4 m01[8], m23[8];
#pragma unroll
    for (int r = 0; r < 4; ++r) {
        f32x4 acc[8];
#pragma unroll
        for (int t = 0; t < 8; ++t) acc[t] = splat4(bo[r * OO + t * 16 + col]);

        const unsigned short* wsb = wstb + (size_t)r * OO * FF + col * FF + grp * 8;
        const unsigned short* wnb = wntb + (size_t)r * OO * FF + col * FF + grp * 8;
        const unsigned short* hp = hfin4 + (size_t)r * NN * FF + (size_t)(n0 + col) * FF + grp * 8;
#pragma unroll
        for (int kt = 0; kt < 4; ++kt) {
            s16x8 ah = *(const s16x8*)(hp + kt * 32);
#pragma unroll
            for (int t = 0; t < 8; ++t) {
                s16x8 b1 = *(const s16x8*)(wsb + t * 16 * FF + kt * 32);
                acc[t] = __builtin_amdgcn_mfma_f32_16x16x32_bf16(af[kt], b1, acc[t], 0, 0, 0);
                s16x8 b2 = *(const s16x8*)(wnb + t * 16 * FF + kt * 32);
                acc[t] = __builtin_amdgcn_mfma_f32_16x16x32_bf16(ah, b2, acc[t], 0, 0, 0);
            }
        }
#pragma unroll
        for (int t = 0; t < 8; ++t) {
            if (r == 0)      m01[t] = acc[t];
            else if (r == 1) { m01[t][0] = fmaxf(m01[t][0], acc[t][0]); m01[t][1] = fmaxf(m01[t][1], acc[t][1]);
                               m01[t][2] = fmaxf(m01[t][2], acc[t][2]); m01[t][3] = fmaxf(m01[t][3], acc[t][3]); }
            else if (r == 2) m23[t] = acc[t];
            else             { m23[t][0] = fmaxf(m23[t][0], acc[t][0]); m23[t][1] = fmaxf(m23[t][1], acc[t][1]);
                               m23[t][2] = fmaxf(m23[t][2], acc[t][2]); m23[t][3] = fmaxf(m23[t][3], acc[t][3]); }
        }
    }
#pragma unroll
    for (int q = 0; q < 4; ++q) {
        int node = n0 + grp * 4 + q;
        int sg = seg[node];
#pragma unroll
        for (int t = 0; t < 8; ++t) {
            int idx = node * OO + t * 16 + col;
            out[idx] = mean[sg * FF + t * 16 + col] + m01[t][q] + m23[t][q];
        }
    }
}

extern "C" void kernel_launch(void* const* d_in, const int* in_sizes, int n_in,
                              void* d_out, int out_size, void* d_ws, size_t ws_size,
                              hipStream_t stream) {
    const float* feat = (const float*)d_in[0];
    const int* nbr[4] = {(const int*)d_in[1], (const int*)d_in[3], (const int*)d_in[5], (const int*)d_in[7]};
    const int* dgp[4] = {(const int*)d_in[2], (const int*)d_in[4], (const int*)d_in[6], (const int*)d_in[8]};
    const int* seg   = (const int*)d_in[9];
    const float* Wih = (const float*)d_in[10];
    const float* Whh = (const float*)d_in[11];
    const float* lb  = (const float*)d_in[12];
    const float* Ws  = (const float*)d_in[13];
    const float* Wn  = (const float*)d_in[14];
    const float* bo  = (const float*)d_in[15];

    char* ws = (char*)d_ws;
    float*          mean  = (float*)(ws + 0);                      //     32,768
    unsigned short* fbf   = (unsigned short*)(ws + 32768);         // 10,240,000
    unsigned short* wihb  = (unsigned short*)(ws + 10272768);      //    524,288
    unsigned short* whhb  = (unsigned short*)(ws + 10797056);      //    524,288
    unsigned short* wstb  = (unsigned short*)(ws + 11321344);      //    131,072
    unsigned short* wntb  = (unsigned short*)(ws + 11452416);      //    131,072
    unsigned short* xih   = (unsigned short*)(ws + 11583488);      // 40,960,000
    unsigned short* hfin4 = (unsigned short*)(ws + 52543488);      // 40,960,000 (4 slices)
    int*            order4= (int*)(ws + 93503488);                 //    655,360
    int*            cnt4  = (int*)(ws + 94158848);                 //      1,024

    hipMemsetAsync(order4, 0xFF, 655360, stream);
    hipMemsetAsync(cnt4, 0, 1024, stream);
    hipMemsetAsync(hfin4, 0, 40960000, stream);

    k_prep<<<256, 256, 0, stream>>>(Wih, Whh, Ws, Wn, wihb, whhb, wstb, wntb);
    k_castfeat<<<5000, 256, 0, stream>>>(feat, fbf);
    k_segmean<<<64, 256, 0, stream>>>(feat, seg, mean);
    k_count<<<dim3(157, 4), 256, 0, stream>>>(dgp[0], dgp[1], dgp[2], dgp[3], cnt4);
    k_offsets<<<1, 64, 0, stream>>>(cnt4);
    k_scatter<<<dim3(157, 4), 256, 0, stream>>>(dgp[0], dgp[1], dgp[2], dgp[3], cnt4, order4);

    for (int r = 0; r < 4; ++r) {
        k_xih<<<2500, 256, 0, stream>>>(fbf, wihb, lb, xih, r);
        k_lstm<<<2560, 256, 0, stream>>>(xih, whhb, order4 + r * 40960, nbr[r], dgp[r],
                                         hfin4 + (size_t)r * NN * FF, r);
    }
    k_proj<<<625, 256, 0, stream>>>(fbf, hfin4, wstb, wntb, bo, mean, seg, (float*)d_out);
}